// Round 1
// baseline (767.772 us; speedup 1.0000x reference)
//
#include <hip/hip_runtime.h>
#include <hip/hip_bf16.h>
#include <cstddef>

// Problem constants
constexpr int BS = 2;
constexpr int N  = 256;
constexpr int D  = 256;   // NH_N
constexpr int E  = 128;   // NH_E
constexpr int YD = 128;   // NH_Y
constexpr float RSQRT_F = 0.17677669529663687f;  // 1/sqrt(32)

// ---------------------------------------------------------------------------
// K1: Q/K/V = x @ W + b   (three 512x256x256 matmuls)
// grid: 3 mats * 64 row-groups, block 256
// ---------------------------------------------------------------------------
__global__ void qkv_kernel(const float* __restrict__ x,
                           const float* __restrict__ qw, const float* __restrict__ qb,
                           const float* __restrict__ kw, const float* __restrict__ kb,
                           const float* __restrict__ vw, const float* __restrict__ vb,
                           float* __restrict__ Q, float* __restrict__ K, float* __restrict__ V) {
    const int m  = blockIdx.x >> 6;    // 0=Q,1=K,2=V
    const int rg = blockIdx.x & 63;    // group of 8 rows out of 512
    const float* W = (m == 0) ? qw : (m == 1) ? kw : vw;
    const float* B = (m == 0) ? qb : (m == 1) ? kb : vb;
    float* O       = (m == 0) ? Q  : (m == 1) ? K  : V;

    __shared__ float xs[8][D];
    const int tid = threadIdx.x;
#pragma unroll
    for (int r = 0; r < 8; ++r)
        xs[r][tid] = x[(size_t)(rg * 8 + r) * D + tid];
    __syncthreads();

    float acc[8];
    const float bb = B[tid];
#pragma unroll
    for (int r = 0; r < 8; ++r) acc[r] = bb;
    for (int k = 0; k < D; ++k) {
        const float w = W[k * D + tid];
#pragma unroll
        for (int r = 0; r < 8; ++r) acc[r] += xs[r][k] * w;
    }
#pragma unroll
    for (int r = 0; r < 8; ++r)
        O[(size_t)(rg * 8 + r) * D + tid] = acc[r];
}

// ---------------------------------------------------------------------------
// K1b: ye1/ye2/yx1/yx2 = y @ W + b  (four 2x128x256 matmuls)
// grid: 2 b * 4 mats, block 256
// ---------------------------------------------------------------------------
__global__ void ymap_kernel(const float* __restrict__ y,
                            const float* __restrict__ we_add, const float* __restrict__ be_add,
                            const float* __restrict__ we_mul, const float* __restrict__ be_mul,
                            const float* __restrict__ wx_add, const float* __restrict__ bx_add,
                            const float* __restrict__ wx_mul, const float* __restrict__ bx_mul,
                            float* __restrict__ ye1, float* __restrict__ ye2,
                            float* __restrict__ yx1, float* __restrict__ yx2) {
    const int b = blockIdx.x >> 2;
    const int m = blockIdx.x & 3;
    const int f = threadIdx.x;
    const float* W; const float* B; float* O;
    switch (m) {
        case 0:  W = we_add; B = be_add; O = ye1; break;
        case 1:  W = we_mul; B = be_mul; O = ye2; break;
        case 2:  W = wx_add; B = bx_add; O = yx1; break;
        default: W = wx_mul; B = bx_mul; O = yx2; break;
    }
    float acc = B[f];
    for (int k = 0; k < YD; ++k)
        acc += y[b * YD + k] * W[k * D + f];
    O[b * D + f] = acc;
}

// ---------------------------------------------------------------------------
// K4a: partial stats of a over j for za  (per block: 256 rows x 128 feats)
// grid: 512 (b*256+chunk), block 128
// ---------------------------------------------------------------------------
__global__ void za_part_kernel(const float* __restrict__ a,
                               float* __restrict__ psum, float* __restrict__ psumsq,
                               float* __restrict__ pmin, float* __restrict__ pmax) {
    const int blk  = blockIdx.x;
    const int feat = threadIdx.x;
    const float* base = a + (size_t)blk * 256 * E + feat;
    float s = 0.f, ss = 0.f, mn = INFINITY, mx = -INFINITY;
    for (int r = 0; r < 256; ++r) {
        const float v = base[(size_t)r * E];
        s += v; ss += v * v; mn = fminf(mn, v); mx = fmaxf(mx, v);
    }
    const int o = blk * E + feat;
    psum[o] = s; psumsq[o] = ss; pmin[o] = mn; pmax[o] = mx;
}

// ---------------------------------------------------------------------------
// K4b: reduce za partials -> za[b][512] = [mean|min|max|std(ddof=1)]
// grid: 2, block 128
// ---------------------------------------------------------------------------
__global__ void za_reduce_kernel(const float* __restrict__ psum, const float* __restrict__ psumsq,
                                 const float* __restrict__ pmin, const float* __restrict__ pmax,
                                 float* __restrict__ za) {
    const int b = blockIdx.x;
    const int feat = threadIdx.x;
    float s = 0.f, ss = 0.f, mn = INFINITY, mx = -INFINITY;
    for (int c = 0; c < 256; ++c) {
        const int o = (b * 256 + c) * E + feat;
        s += psum[o]; ss += psumsq[o];
        mn = fminf(mn, pmin[o]); mx = fmaxf(mx, pmax[o]);
    }
    const float M = 65536.f;
    const float mean = s / M;
    const float var  = (ss - s * s / M) / (M - 1.f);
    za[b * 512 + feat]           = mean;
    za[b * 512 + 128 + feat]     = mn;
    za[b * 512 + 256 + feat]     = mx;
    za[b * 512 + 384 + feat]     = sqrtf(fmaxf(var, 0.f));
}

// ---------------------------------------------------------------------------
// K4c: zx[b][1024] = [mean|min|max|std(ddof=1)] of x over axis 1
// grid: 2, block 256
// ---------------------------------------------------------------------------
__global__ void zx_kernel(const float* __restrict__ x, float* __restrict__ zx) {
    const int b = blockIdx.x;
    const int f = threadIdx.x;
    float s = 0.f, ss = 0.f, mn = INFINITY, mx = -INFINITY;
    for (int i = 0; i < N; ++i) {
        const float v = x[((size_t)b * N + i) * D + f];
        s += v; ss += v * v; mn = fminf(mn, v); mx = fmaxf(mx, v);
    }
    const float M = 256.f;
    const float mean = s / M;
    const float var  = (ss - s * s / M) / (M - 1.f);
    zx[b * 1024 + f]        = mean;
    zx[b * 1024 + 256 + f]  = mn;
    zx[b * 1024 + 512 + f]  = mx;
    zx[b * 1024 + 768 + f]  = sqrtf(fmaxf(var, 0.f));
}

// ---------------------------------------------------------------------------
// K2 (main): per block = one (b,i). Fused: a1/a2 GEMMs, Y, ahat GEMM + store,
// online softmax over j + weighted-V accumulation -> wV.
// grid: 512, block 512
// ---------------------------------------------------------------------------
__global__ __launch_bounds__(512) void main_kernel(
        const float* __restrict__ a,
        const float* __restrict__ Wadd, const float* __restrict__ Badd,
        const float* __restrict__ Wmul, const float* __restrict__ Bmul,
        const float* __restrict__ AoutW, const float* __restrict__ AoutB,
        const float* __restrict__ Qb, const float* __restrict__ Kb, const float* __restrict__ Vb,
        const float* __restrict__ ye1, const float* __restrict__ ye2,
        float* __restrict__ ahat, float* __restrict__ wV) {
    const int blk = blockIdx.x;        // b*256 + i
    const int b = blk >> 8;
    const int i = blk & 255;
    const int tid = threadIdx.x;
    const int f  = tid & 255;
    const int jh = tid >> 8;           // 0 or 1

    __shared__ float buf[64 * 256];    // union: a-tile [64][128] then h-tile [64][256]
    __shared__ float qrow[D], y1s[D], y2s[D];
    __shared__ float red_m[512], red_l[512], red_a[512];

    if (tid < 256) {
        qrow[tid] = Qb[((size_t)b * N + i) * D + tid];
        y1s[tid]  = ye1[b * D + tid];
        y2s[tid]  = ye2[b * D + tid];
    }

    float m = -INFINITY, l = 0.f, accv = 0.f;
    const float badd_f = Badd[f];
    const float bmul_f = Bmul[f];
    const float* arow = a + ((size_t)b * N + i) * N * E;   // (256,128)

    for (int t = 0; t < 4; ++t) {
        const int j0 = t * 64;
        __syncthreads();
        // ---- P0: load a tile (64x128 contiguous floats) ----
        {
            const float4* src = (const float4*)(arow + (size_t)j0 * E);
            float4* dst = (float4*)buf;
#pragma unroll
            for (int u = 0; u < 4; ++u)
                dst[tid + u * 512] = src[tid + u * 512];
        }
        __syncthreads();
        // ---- P1: t1 = a@Wadd+b, t2 = a@Wmul+b for this thread's (jh, f) ----
        float t1[32], t2[32];
#pragma unroll
        for (int jj = 0; jj < 32; ++jj) { t1[jj] = badd_f; t2[jj] = bmul_f; }
        const float* abase = buf + jh * 32 * E;
        for (int k4 = 0; k4 < 32; ++k4) {
            const int k = 4 * k4;
            const float wa0 = Wadd[(k + 0) * D + f];
            const float wa1 = Wadd[(k + 1) * D + f];
            const float wa2 = Wadd[(k + 2) * D + f];
            const float wa3 = Wadd[(k + 3) * D + f];
            const float wm0 = Wmul[(k + 0) * D + f];
            const float wm1 = Wmul[(k + 1) * D + f];
            const float wm2 = Wmul[(k + 2) * D + f];
            const float wm3 = Wmul[(k + 3) * D + f];
#pragma unroll
            for (int jj = 0; jj < 32; ++jj) {
                const float4 av = *(const float4*)(abase + jj * E + k);
                t1[jj] += av.x * wa0 + av.y * wa1 + av.z * wa2 + av.w * wa3;
                t2[jj] += av.x * wm0 + av.y * wm1 + av.z * wm2 + av.w * wm3;
            }
        }
        __syncthreads();   // done reading a-tile; buf will be overwritten with h
        // ---- P2: Y, h, online softmax + V accumulation ----
        const float qf = qrow[f];
        const float e1f = y1s[f];
        const float e2f = y2s[f] + 1.f;
#pragma unroll
        for (int jj = 0; jj < 32; ++jj) {
            const int jl = jh * 32 + jj;
            const int j  = j0 + jl;
            const float kv = Kb[((size_t)b * N + j) * D + f];
            const float vv = Vb[((size_t)b * N + j) * D + f];
            const float yv = qf * kv * RSQRT_F * (t1[jj] + 1.f) + t2[jj];
            buf[jl * D + f] = e1f + e2f * yv;
            const float mn = fmaxf(m, yv);
            const float sc = __expf(m - mn);
            const float ev = __expf(yv - mn);
            l    = l * sc + ev;
            accv = accv * sc + ev * vv;
            m = mn;
        }
        __syncthreads();
        // ---- P3: ahat = h @ AoutW + AoutB, store ----
        {
            const int e_ = tid & 127;
            const int g  = tid >> 7;        // 0..3, 16 j's each
            float oacc[16];
            const float ob = AoutB[e_];
#pragma unroll
            for (int jj = 0; jj < 16; ++jj) oacc[jj] = ob;
            for (int f4 = 0; f4 < 64; ++f4) {
                const int fk = 4 * f4;
                const float w0 = AoutW[(fk + 0) * E + e_];
                const float w1 = AoutW[(fk + 1) * E + e_];
                const float w2 = AoutW[(fk + 2) * E + e_];
                const float w3 = AoutW[(fk + 3) * E + e_];
#pragma unroll
                for (int jj = 0; jj < 16; ++jj) {
                    const float4 hv = *(const float4*)(buf + (g * 16 + jj) * D + fk);
                    oacc[jj] += hv.x * w0 + hv.y * w1 + hv.z * w2 + hv.w * w3;
                }
            }
#pragma unroll
            for (int jj = 0; jj < 16; ++jj) {
                const int j = j0 + g * 16 + jj;
                ahat[(((size_t)b * N + i) * N + j) * E + e_] = oacc[jj];
            }
        }
    }
    // ---- merge the two j-halves' softmax states, write wV ----
    red_m[tid] = m; red_l[tid] = l; red_a[tid] = accv;
    __syncthreads();
    if (tid < 256) {
        const float m0 = red_m[tid], m1 = red_m[tid + 256];
        const float M  = fmaxf(m0, m1);
        const float e0 = __expf(m0 - M), e1 = __expf(m1 - M);
        const float L  = red_l[tid] * e0 + red_l[tid + 256] * e1;
        const float A  = red_a[tid] * e0 + red_a[tid + 256] * e1;
        wV[((size_t)b * N + i) * D + tid] = A / L;
    }
}

// ---------------------------------------------------------------------------
// K3: xhat = (yx1 + (yx2+1)*wV) @ x_out_w + x_out_b
// grid: 64 (8 rows each), block 256
// ---------------------------------------------------------------------------
__global__ void xhat_kernel(const float* __restrict__ wV,
                            const float* __restrict__ yx1, const float* __restrict__ yx2,
                            const float* __restrict__ W, const float* __restrict__ B,
                            float* __restrict__ out) {
    const int rg = blockIdx.x;
    const int tid = threadIdx.x;
    __shared__ float xr[8][D];
#pragma unroll
    for (int r = 0; r < 8; ++r) {
        const int row = rg * 8 + r;
        const int b = row >> 8;
        xr[r][tid] = yx1[b * D + tid] + (yx2[b * D + tid] + 1.f) * wV[(size_t)row * D + tid];
    }
    __syncthreads();
    float acc[8];
    const float bb = B[tid];
#pragma unroll
    for (int r = 0; r < 8; ++r) acc[r] = bb;
    for (int k = 0; k < D; ++k) {
        const float w = W[k * D + tid];
#pragma unroll
        for (int r = 0; r < 8; ++r) acc[r] += xr[r][k] * w;
    }
#pragma unroll
    for (int r = 0; r < 8; ++r)
        out[(size_t)(rg * 8 + r) * D + tid] = acc[r];
}

// ---------------------------------------------------------------------------
// K5: yhat = MLP(lin(y)+lin(za)+lin(zx))
// grid: 2, block 128
// ---------------------------------------------------------------------------
__global__ void yhat_kernel(const float* __restrict__ y,
                            const float* __restrict__ za, const float* __restrict__ zx,
                            const float* __restrict__ yyw, const float* __restrict__ yyb,
                            const float* __restrict__ xyw, const float* __restrict__ xyb,
                            const float* __restrict__ ayw, const float* __restrict__ ayb,
                            const float* __restrict__ w1, const float* __restrict__ b1,
                            const float* __restrict__ w2, const float* __restrict__ b2,
                            float* __restrict__ out) {
    const int b = blockIdx.x;
    const int o = threadIdx.x;
    __shared__ float h1[YD], h2[YD];
    float acc = yyb[o] + xyb[o] + ayb[o];
    for (int k = 0; k < YD; ++k)   acc += y[b * YD + k]   * yyw[k * YD + o];
    for (int k = 0; k < 512; ++k)  acc += za[b * 512 + k] * ayw[k * YD + o];
    for (int k = 0; k < 1024; ++k) acc += zx[b * 1024 + k] * xyw[k * YD + o];
    h1[o] = acc;
    __syncthreads();
    float acc2 = b1[o];
    for (int k = 0; k < YD; ++k) acc2 += h1[k] * w1[k * YD + o];
    h2[o] = fmaxf(acc2, 0.f);
    __syncthreads();
    float acc3 = b2[o];
    for (int k = 0; k < YD; ++k) acc3 += h2[k] * w2[k * YD + o];
    out[b * YD + o] = acc3;
}

// ---------------------------------------------------------------------------
extern "C" void kernel_launch(void* const* d_in, const int* in_sizes, int n_in,
                              void* d_out, int out_size, void* d_ws, size_t ws_size,
                              hipStream_t stream) {
    const float* x         = (const float*)d_in[0];
    const float* a         = (const float*)d_in[1];
    const float* y         = (const float*)d_in[2];
    const float* qw        = (const float*)d_in[3];  const float* qb        = (const float*)d_in[4];
    const float* kw        = (const float*)d_in[5];  const float* kb        = (const float*)d_in[6];
    const float* vw        = (const float*)d_in[7];  const float* vb        = (const float*)d_in[8];
    const float* a2x_add_w = (const float*)d_in[9];  const float* a2x_add_b = (const float*)d_in[10];
    const float* a2x_mul_w = (const float*)d_in[11]; const float* a2x_mul_b = (const float*)d_in[12];
    const float* y2e_mul_w = (const float*)d_in[13]; const float* y2e_mul_b = (const float*)d_in[14];
    const float* y2e_add_w = (const float*)d_in[15]; const float* y2e_add_b = (const float*)d_in[16];
    const float* y2x_mul_w = (const float*)d_in[17]; const float* y2x_mul_b = (const float*)d_in[18];
    const float* y2x_add_w = (const float*)d_in[19]; const float* y2x_add_b = (const float*)d_in[20];
    const float* y_y_w     = (const float*)d_in[21]; const float* y_y_b     = (const float*)d_in[22];
    const float* x_y_w     = (const float*)d_in[23]; const float* x_y_b     = (const float*)d_in[24];
    const float* a_y_w     = (const float*)d_in[25]; const float* a_y_b     = (const float*)d_in[26];
    const float* x_out_w   = (const float*)d_in[27]; const float* x_out_b   = (const float*)d_in[28];
    const float* a_out_w   = (const float*)d_in[29]; const float* a_out_b   = (const float*)d_in[30];
    const float* y_out1_w  = (const float*)d_in[31]; const float* y_out1_b  = (const float*)d_in[32];
    const float* y_out2_w  = (const float*)d_in[33]; const float* y_out2_b  = (const float*)d_in[34];

    float* ws    = (float*)d_ws;
    float* Q     = ws;
    float* Kb    = ws + 131072;
    float* Vb    = ws + 262144;
    float* wV    = ws + 393216;
    float* ye1   = ws + 524288;
    float* ye2   = ws + 524800;
    float* yx1   = ws + 525312;
    float* yx2   = ws + 525824;
    float* psum  = ws + 526336;
    float* psumsq= ws + 591872;
    float* pminb = ws + 657408;
    float* pmaxb = ws + 722944;
    float* za    = ws + 788480;
    float* zx    = ws + 789504;

    float* xhat = (float*)d_out;                 // 2*256*256
    float* ahat = (float*)d_out + 131072;        // 2*256*256*128
    float* yhat = (float*)d_out + 16908288;      // 2*128

    qkv_kernel<<<192, 256, 0, stream>>>(x, qw, qb, kw, kb, vw, vb, Q, Kb, Vb);
    ymap_kernel<<<8, 256, 0, stream>>>(y, y2e_add_w, y2e_add_b, y2e_mul_w, y2e_mul_b,
                                       y2x_add_w, y2x_add_b, y2x_mul_w, y2x_mul_b,
                                       ye1, ye2, yx1, yx2);
    za_part_kernel<<<512, 128, 0, stream>>>(a, psum, psumsq, pminb, pmaxb);
    zx_kernel<<<2, 256, 0, stream>>>(x, zx);
    main_kernel<<<512, 512, 0, stream>>>(a, a2x_add_w, a2x_add_b, a2x_mul_w, a2x_mul_b,
                                         a_out_w, a_out_b, Q, Kb, Vb, ye1, ye2, ahat, wV);
    xhat_kernel<<<64, 256, 0, stream>>>(wV, yx1, yx2, x_out_w, x_out_b, xhat);
    za_reduce_kernel<<<2, 128, 0, stream>>>(psum, psumsq, pminb, pmaxb, za);
    yhat_kernel<<<2, 128, 0, stream>>>(y, za, zx, y_y_w, y_y_b, x_y_w, x_y_b, a_y_w, a_y_b,
                                       y_out1_w, y_out1_b, y_out2_w, y_out2_b, yhat);
}

// Round 2
// 418.854 us; speedup vs baseline: 1.8330x; 1.8330x over previous
//
#include <hip/hip_runtime.h>
#include <hip/hip_bf16.h>
#include <cstddef>

// Problem constants
constexpr int BS = 2;
constexpr int N  = 256;
constexpr int D  = 256;   // NH_N
constexpr int E  = 128;   // NH_E
constexpr int YD = 128;   // NH_Y
constexpr float RSQRT_F = 0.17677669529663687f;  // 1/sqrt(32)

typedef __attribute__((ext_vector_type(8))) short     short8;
typedef __attribute__((ext_vector_type(4))) float     f32x4;
typedef __attribute__((ext_vector_type(2))) float     f32x2;
typedef __attribute__((ext_vector_type(4))) unsigned short u16x4;
typedef __attribute__((ext_vector_type(8))) unsigned short u16x8;

__device__ __forceinline__ unsigned short f2bf(float x) {
    unsigned u = __float_as_uint(x);
    unsigned r = (u + 0x7fffu + ((u >> 16) & 1u)) >> 16;   // RNE
    return (unsigned short)r;
}
__device__ __forceinline__ float bf2f(unsigned short h) {
    return __uint_as_float(((unsigned)h) << 16);
}
__device__ __forceinline__ f32x4 mfma16(short8 a, short8 b, f32x4 c) {
    return __builtin_amdgcn_mfma_f32_16x16x32_bf16(a, b, c, 0, 0, 0);
}

// ---------------------------------------------------------------------------
// prep: transpose + bf16-convert the three big weight matrices
// WaddT[f][e]=Wadd[e][f], WmulT[f][e]=Wmul[e][f]  (256x128 bf16)
// W2T[e][f]=W2[f][e]                              (128x256 bf16)
// grid 384, block 256
// ---------------------------------------------------------------------------
__global__ void wt_kernel(const float* __restrict__ Wadd, const float* __restrict__ Wmul,
                          const float* __restrict__ W2,
                          unsigned short* __restrict__ WaddT, unsigned short* __restrict__ WmulT,
                          unsigned short* __restrict__ W2T) {
    int idx = blockIdx.x * 256 + threadIdx.x;
    int s = idx >> 15;          // 32768 per section
    int k = idx & 32767;
    if (s == 0)      { int f = k >> 7, e = k & 127; WaddT[k] = f2bf(Wadd[e * 256 + f]); }
    else if (s == 1) { int f = k >> 7, e = k & 127; WmulT[k] = f2bf(Wmul[e * 256 + f]); }
    else             { int f = k & 255, e = k >> 8; W2T[k]   = f2bf(W2[f * 128 + e]); }
}

// ---------------------------------------------------------------------------
// K1: Q = x@qw+qb ; kvpack[row][f] = (K,V) interleaved f32x2
// grid: 3*64, block 256
// ---------------------------------------------------------------------------
__global__ void qkv_kernel(const float* __restrict__ x,
                           const float* __restrict__ qw, const float* __restrict__ qb,
                           const float* __restrict__ kw, const float* __restrict__ kb,
                           const float* __restrict__ vw, const float* __restrict__ vb,
                           float* __restrict__ Q, float* __restrict__ kv) {
    const int m  = blockIdx.x >> 6;
    const int rg = blockIdx.x & 63;
    const float* W = (m == 0) ? qw : (m == 1) ? kw : vw;
    const float* B = (m == 0) ? qb : (m == 1) ? kb : vb;

    __shared__ float xs[8][D];
    const int tid = threadIdx.x;
#pragma unroll
    for (int r = 0; r < 8; ++r)
        xs[r][tid] = x[(size_t)(rg * 8 + r) * D + tid];
    __syncthreads();

    float acc[8];
    const float bb = B[tid];
#pragma unroll
    for (int r = 0; r < 8; ++r) acc[r] = bb;
    for (int k = 0; k < D; ++k) {
        const float w = W[k * D + tid];
#pragma unroll
        for (int r = 0; r < 8; ++r) acc[r] += xs[r][k] * w;
    }
#pragma unroll
    for (int r = 0; r < 8; ++r) {
        const int row = rg * 8 + r;
        if (m == 0) Q[(size_t)row * D + tid] = acc[r];
        else        kv[((size_t)row * D + tid) * 2 + (m - 1)] = acc[r];
    }
}

// ---------------------------------------------------------------------------
// ymap: ye1/ye2/yx1/yx2 = y @ W + b
// ---------------------------------------------------------------------------
__global__ void ymap_kernel(const float* __restrict__ y,
                            const float* __restrict__ we_add, const float* __restrict__ be_add,
                            const float* __restrict__ we_mul, const float* __restrict__ be_mul,
                            const float* __restrict__ wx_add, const float* __restrict__ bx_add,
                            const float* __restrict__ wx_mul, const float* __restrict__ bx_mul,
                            float* __restrict__ ye1, float* __restrict__ ye2,
                            float* __restrict__ yx1, float* __restrict__ yx2) {
    const int b = blockIdx.x >> 2;
    const int m = blockIdx.x & 3;
    const int f = threadIdx.x;
    const float* W; const float* B; float* O;
    switch (m) {
        case 0:  W = we_add; B = be_add; O = ye1; break;
        case 1:  W = we_mul; B = be_mul; O = ye2; break;
        case 2:  W = wx_add; B = bx_add; O = yx1; break;
        default: W = wx_mul; B = bx_mul; O = yx2; break;
    }
    float acc = B[f];
    for (int k = 0; k < YD; ++k)
        acc += y[b * YD + k] * W[k * D + f];
    O[b * D + f] = acc;
}

// ---------------------------------------------------------------------------
// za partial stats
// ---------------------------------------------------------------------------
__global__ void za_part_kernel(const float* __restrict__ a,
                               float* __restrict__ psum, float* __restrict__ psumsq,
                               float* __restrict__ pmin, float* __restrict__ pmax) {
    const int blk  = blockIdx.x;
    const int feat = threadIdx.x;
    const float* base = a + (size_t)blk * 256 * E + feat;
    float s = 0.f, ss = 0.f, mn = INFINITY, mx = -INFINITY;
    for (int r = 0; r < 256; ++r) {
        const float v = base[(size_t)r * E];
        s += v; ss += v * v; mn = fminf(mn, v); mx = fmaxf(mx, v);
    }
    const int o = blk * E + feat;
    psum[o] = s; psumsq[o] = ss; pmin[o] = mn; pmax[o] = mx;
}

__global__ void za_reduce_kernel(const float* __restrict__ psum, const float* __restrict__ psumsq,
                                 const float* __restrict__ pmin, const float* __restrict__ pmax,
                                 float* __restrict__ za) {
    const int b = blockIdx.x;
    const int feat = threadIdx.x;
    float s = 0.f, ss = 0.f, mn = INFINITY, mx = -INFINITY;
    for (int c = 0; c < 256; ++c) {
        const int o = (b * 256 + c) * E + feat;
        s += psum[o]; ss += psumsq[o];
        mn = fminf(mn, pmin[o]); mx = fmaxf(mx, pmax[o]);
    }
    const float M = 65536.f;
    const float mean = s / M;
    const float var  = (ss - s * s / M) / (M - 1.f);
    za[b * 512 + feat]       = mean;
    za[b * 512 + 128 + feat] = mn;
    za[b * 512 + 256 + feat] = mx;
    za[b * 512 + 384 + feat] = sqrtf(fmaxf(var, 0.f));
}

__global__ void zx_kernel(const float* __restrict__ x, float* __restrict__ zx) {
    const int b = blockIdx.x;
    const int f = threadIdx.x;
    float s = 0.f, ss = 0.f, mn = INFINITY, mx = -INFINITY;
    for (int i = 0; i < N; ++i) {
        const float v = x[((size_t)b * N + i) * D + f];
        s += v; ss += v * v; mn = fminf(mn, v); mx = fmaxf(mx, v);
    }
    const float M = 256.f;
    const float mean = s / M;
    const float var  = (ss - s * s / M) / (M - 1.f);
    zx[b * 1024 + f]       = mean;
    zx[b * 1024 + 256 + f] = mn;
    zx[b * 1024 + 512 + f] = mx;
    zx[b * 1024 + 768 + f] = sqrtf(fmaxf(var, 0.f));
}

// ---------------------------------------------------------------------------
// MAIN: per block = one (b,i). 8 waves, j in 4 passes of 64.
// GEMM1 (MFMA): t12buf[f][j] pairs (a1,a2)^T ; phase B: softmax + h ;
// GEMM2 (MFMA): ahat^T = W2T @ h^T ; wV via online softmax state.
// ---------------------------------------------------------------------------
__global__ __launch_bounds__(512, 2) void main_kernel(
        const float* __restrict__ a,
        const unsigned short* __restrict__ WaddT, const float* __restrict__ Badd,
        const unsigned short* __restrict__ WmulT, const float* __restrict__ Bmul,
        const unsigned short* __restrict__ W2T,  const float* __restrict__ AoutB,
        const float* __restrict__ Q, const float* __restrict__ kv,
        const float* __restrict__ ye1, const float* __restrict__ ye2,
        float* __restrict__ ahat, float* __restrict__ wV) {
    const int bi = blockIdx.x;         // b*256 + i
    const int b  = bi >> 8;
    const int tid  = threadIdx.x;
    const int lane = tid & 63;
    const int wid  = tid >> 6;
    const int l15  = lane & 15;
    const int lk   = lane >> 4;        // 0..3
    const int mw   = wid & 3;          // f-block (GEMM1) / e-block (GEMM2)
    const int jw   = wid >> 2;         // j-block (0/1)

    __shared__ unsigned short abuf[64 * 128];   // 16 KB  a-tile bf16 (swizzled)
    __shared__ unsigned short tbuf[64 * 512];   // 64 KB  (t1,t2) interleaved bf16
    __shared__ unsigned short hbuf[64 * 256];   // 32 KB  h bf16 (swizzled)

    const float* arow  = a + (size_t)bi * N * E;
    float* ahatp       = ahat + (size_t)bi * N * E;

    // phase-B per-thread constants
    const int   f   = tid & 255;
    const int   jh  = tid >> 8;                  // j half within pass
    const float qs  = Q[(size_t)bi * D + f] * RSQRT_F;
    const float e1  = ye1[b * D + f];
    const float e2  = ye2[b * D + f] + 1.f;
    const float badd = Badd[f];
    const float bmul = Bmul[f];
    float sm_m = -INFINITY, sm_l = 0.f, sm_a = 0.f;

    // GEMM2 bias frags (e depends only on lane/wave)
    f32x4 bias2[2];
#pragma unroll
    for (int m2 = 0; m2 < 2; ++m2)
        bias2[m2] = *(const f32x4*)(AoutB + mw * 32 + m2 * 16 + lk * 4);

    for (int t = 0; t < 4; ++t) {
        const int j0 = t * 64;
        __syncthreads();   // (a) previous pass fully done with all LDS buffers

        // ---- stage a-tile -> bf16 LDS (swizzled) ----
#pragma unroll
        for (int u = 0; u < 4; ++u) {
            const int q  = tid + u * 512;       // quad index, 2048 total
            const int jl = q >> 5;
            const int eq = q & 31;
            const f32x4 v = *(const f32x4*)(arow + (size_t)(j0 + jl) * E + eq * 4);
            u16x4 p;
            p.x = f2bf(v.x); p.y = f2bf(v.y); p.z = f2bf(v.z); p.w = f2bf(v.w);
            unsigned addr = (unsigned)(jl * 256 + eq * 8) ^ ((jl & 7) << 4);
            *(u16x4*)((char*)abuf + addr) = p;
        }
        __syncthreads();   // (b) a-tile ready

        // ---- GEMM1: acc[f][j] for Wadd and Wmul ----
        f32x4 acc1[4][2], acc2[4][2];
#pragma unroll
        for (int m_ = 0; m_ < 4; ++m_)
#pragma unroll
            for (int n_ = 0; n_ < 2; ++n_) {
                acc1[m_][n_] = (f32x4){0.f, 0.f, 0.f, 0.f};
                acc2[m_][n_] = (f32x4){0.f, 0.f, 0.f, 0.f};
            }
#pragma unroll
        for (int ks = 0; ks < 4; ++ks) {
            const int eoff = ks * 32 + lk * 8;
            short8 bfrg[2];
#pragma unroll
            for (int n_ = 0; n_ < 2; ++n_) {
                const int jl = jw * 32 + n_ * 16 + l15;
                unsigned addr = (unsigned)(jl * 256 + eoff * 2) ^ ((jl & 7) << 4);
                bfrg[n_] = *(const short8*)((const char*)abuf + addr);
            }
#pragma unroll
            for (int m_ = 0; m_ < 4; ++m_) {
                const int frow = mw * 64 + m_ * 16 + l15;
                const short8 wa = *(const short8*)(WaddT + frow * 128 + eoff);
                const short8 wm = *(const short8*)(WmulT + frow * 128 + eoff);
#pragma unroll
                for (int n_ = 0; n_ < 2; ++n_) {
                    acc1[m_][n_] = mfma16(wa, bfrg[n_], acc1[m_][n_]);
                    acc2[m_][n_] = mfma16(wm, bfrg[n_], acc2[m_][n_]);
                }
            }
        }
        // ---- write (t1,t2) interleaved frags ----
#pragma unroll
        for (int m_ = 0; m_ < 4; ++m_)
#pragma unroll
            for (int n_ = 0; n_ < 2; ++n_) {
                const int jl = jw * 32 + n_ * 16 + l15;
                const int fb = mw * 64 + m_ * 16 + lk * 4;
                u16x8 p;
                p.s0 = f2bf(acc1[m_][n_].x); p.s1 = f2bf(acc2[m_][n_].x);
                p.s2 = f2bf(acc1[m_][n_].y); p.s3 = f2bf(acc2[m_][n_].y);
                p.s4 = f2bf(acc1[m_][n_].z); p.s5 = f2bf(acc2[m_][n_].z);
                p.s6 = f2bf(acc1[m_][n_].w); p.s7 = f2bf(acc2[m_][n_].w);
                unsigned addr = (unsigned)(jl * 1024 + fb * 4) ^ ((jl & 7) << 4);
                *(u16x8*)((char*)tbuf + addr) = p;
            }
        __syncthreads();   // (c) t1/t2 ready

        // ---- phase B: Y, h, online softmax (thread = f, loop j) ----
#pragma unroll 4
        for (int jj = 0; jj < 32; ++jj) {
            const int jl = jh * 32 + jj;
            const int jg = j0 + jl;
            const unsigned taddr = (unsigned)(jl * 1024 + f * 4) ^ ((jl & 7) << 4);
            const unsigned tt = *(const unsigned*)((const char*)tbuf + taddr);
            const float t1 = bf2f((unsigned short)(tt & 0xffffu)) + badd;
            const float t2 = bf2f((unsigned short)(tt >> 16)) + bmul;
            const f32x2 kvv = *(const f32x2*)(kv + ((size_t)(b * N + jg) * D + f) * 2);
            const float yv = qs * kvv.x * (t1 + 1.f) + t2;
            const float hv = e1 + e2 * yv;
            const unsigned haddr = (unsigned)(jl * 512 + f * 2) ^ ((jl & 7) << 4);
            *(unsigned short*)((char*)hbuf + haddr) = f2bf(hv);
            const float mn = fmaxf(sm_m, yv);
            const float sc = __expf(sm_m - mn);
            const float ev = __expf(yv - mn);
            sm_l = sm_l * sc + ev;
            sm_a = sm_a * sc + ev * kvv.y;
            sm_m = mn;
        }
        __syncthreads();   // (d) h ready

        // ---- GEMM2: ahat^T[e][j] = W2T @ h^T ----
        f32x4 accO[2][2];
#pragma unroll
        for (int m2 = 0; m2 < 2; ++m2)
#pragma unroll
            for (int n2 = 0; n2 < 2; ++n2)
                accO[m2][n2] = (f32x4){0.f, 0.f, 0.f, 0.f};
#pragma unroll
        for (int ks = 0; ks < 8; ++ks) {
            const int foff = ks * 32 + lk * 8;
            short8 hb[2];
#pragma unroll
            for (int n2 = 0; n2 < 2; ++n2) {
                const int jl = jw * 32 + n2 * 16 + l15;
                unsigned addr = (unsigned)(jl * 512 + foff * 2) ^ ((jl & 7) << 4);
                hb[n2] = *(const short8*)((const char*)hbuf + addr);
            }
#pragma unroll
            for (int m2 = 0; m2 < 2; ++m2) {
                const int erow = mw * 32 + m2 * 16 + l15;
                const short8 w2 = *(const short8*)(W2T + erow * 256 + foff);
#pragma unroll
                for (int n2 = 0; n2 < 2; ++n2)
                    accO[m2][n2] = mfma16(w2, hb[n2], accO[m2][n2]);
            }
        }
#pragma unroll
        for (int m2 = 0; m2 < 2; ++m2)
#pragma unroll
            for (int n2 = 0; n2 < 2; ++n2) {
                const int eb = mw * 32 + m2 * 16 + lk * 4;
                const int jg = j0 + jw * 32 + n2 * 16 + l15;
                f32x4 ov = accO[m2][n2] + bias2[m2];
                *(f32x4*)(ahatp + (size_t)jg * E + eb) = ov;
            }
    }

    // ---- merge the two j-half softmax states, write wV ----
    float* redm = (float*)abuf;          // reuse abuf (a-tile no longer needed)
    float* redl = redm + 512;
    float* reda = redl + 512;
    __syncthreads();
    redm[tid] = sm_m; redl[tid] = sm_l; reda[tid] = sm_a;
    __syncthreads();
    if (tid < 256) {
        const float m0 = redm[tid], m1 = redm[tid + 256];
        const float M  = fmaxf(m0, m1);
        const float e0 = __expf(m0 - M), e1m = __expf(m1 - M);
        const float L  = redl[tid] * e0 + redl[tid + 256] * e1m;
        const float A  = reda[tid] * e0 + reda[tid + 256] * e1m;
        wV[(size_t)bi * D + tid] = A / L;
    }
}

// ---------------------------------------------------------------------------
// xhat = (yx1 + (yx2+1)*wV) @ x_out_w + x_out_b
// ---------------------------------------------------------------------------
__global__ void xhat_kernel(const float* __restrict__ wV,
                            const float* __restrict__ yx1, const float* __restrict__ yx2,
                            const float* __restrict__ W, const float* __restrict__ B,
                            float* __restrict__ out) {
    const int rg = blockIdx.x;
    const int tid = threadIdx.x;
    __shared__ float xr[8][D];
#pragma unroll
    for (int r = 0; r < 8; ++r) {
        const int row = rg * 8 + r;
        const int b = row >> 8;
        xr[r][tid] = yx1[b * D + tid] + (yx2[b * D + tid] + 1.f) * wV[(size_t)row * D + tid];
    }
    __syncthreads();
    float acc[8];
    const float bb = B[tid];
#pragma unroll
    for (int r = 0; r < 8; ++r) acc[r] = bb;
    for (int k = 0; k < D; ++k) {
        const float w = W[k * D + tid];
#pragma unroll
        for (int r = 0; r < 8; ++r) acc[r] += xr[r][k] * w;
    }
#pragma unroll
    for (int r = 0; r < 8; ++r)
        out[(size_t)(rg * 8 + r) * D + tid] = acc[r];
}

// ---------------------------------------------------------------------------
// yhat MLP
// ---------------------------------------------------------------------------
__global__ void yhat_kernel(const float* __restrict__ y,
                            const float* __restrict__ za, const float* __restrict__ zx,
                            const float* __restrict__ yyw, const float* __restrict__ yyb,
                            const float* __restrict__ xyw, const float* __restrict__ xyb,
                            const float* __restrict__ ayw, const float* __restrict__ ayb,
                            const float* __restrict__ w1, const float* __restrict__ b1,
                            const float* __restrict__ w2, const float* __restrict__ b2,
                            float* __restrict__ out) {
    const int b = blockIdx.x;
    const int o = threadIdx.x;
    __shared__ float h1[YD], h2[YD];
    float acc = yyb[o] + xyb[o] + ayb[o];
    for (int k = 0; k < YD; ++k)   acc += y[b * YD + k]    * yyw[k * YD + o];
    for (int k = 0; k < 512; ++k)  acc += za[b * 512 + k]  * ayw[k * YD + o];
    for (int k = 0; k < 1024; ++k) acc += zx[b * 1024 + k] * xyw[k * YD + o];
    h1[o] = acc;
    __syncthreads();
    float acc2 = b1[o];
    for (int k = 0; k < YD; ++k) acc2 += h1[k] * w1[k * YD + o];
    h2[o] = fmaxf(acc2, 0.f);
    __syncthreads();
    float acc3 = b2[o];
    for (int k = 0; k < YD; ++k) acc3 += h2[k] * w2[k * YD + o];
    out[b * YD + o] = acc3;
}

// ---------------------------------------------------------------------------
extern "C" void kernel_launch(void* const* d_in, const int* in_sizes, int n_in,
                              void* d_out, int out_size, void* d_ws, size_t ws_size,
                              hipStream_t stream) {
    const float* x         = (const float*)d_in[0];
    const float* a         = (const float*)d_in[1];
    const float* y         = (const float*)d_in[2];
    const float* qw        = (const float*)d_in[3];  const float* qb        = (const float*)d_in[4];
    const float* kw        = (const float*)d_in[5];  const float* kb        = (const float*)d_in[6];
    const float* vw        = (const float*)d_in[7];  const float* vb        = (const float*)d_in[8];
    const float* a2x_add_w = (const float*)d_in[9];  const float* a2x_add_b = (const float*)d_in[10];
    const float* a2x_mul_w = (const float*)d_in[11]; const float* a2x_mul_b = (const float*)d_in[12];
    const float* y2e_mul_w = (const float*)d_in[13]; const float* y2e_mul_b = (const float*)d_in[14];
    const float* y2e_add_w = (const float*)d_in[15]; const float* y2e_add_b = (const float*)d_in[16];
    const float* y2x_mul_w = (const float*)d_in[17]; const float* y2x_mul_b = (const float*)d_in[18];
    const float* y2x_add_w = (const float*)d_in[19]; const float* y2x_add_b = (const float*)d_in[20];
    const float* y_y_w     = (const float*)d_in[21]; const float* y_y_b     = (const float*)d_in[22];
    const float* x_y_w     = (const float*)d_in[23]; const float* x_y_b     = (const float*)d_in[24];
    const float* a_y_w     = (const float*)d_in[25]; const float* a_y_b     = (const float*)d_in[26];
    const float* x_out_w   = (const float*)d_in[27]; const float* x_out_b   = (const float*)d_in[28];
    const float* a_out_w   = (const float*)d_in[29]; const float* a_out_b   = (const float*)d_in[30];
    const float* y_out1_w  = (const float*)d_in[31]; const float* y_out1_b  = (const float*)d_in[32];
    const float* y_out2_w  = (const float*)d_in[33]; const float* y_out2_b  = (const float*)d_in[34];

    float* ws = (float*)d_ws;
    float* Q      = ws;                 // 131072
    float* kv     = ws + 131072;        // 262144 (K,V interleaved)
    float* wV     = ws + 393216;        // 131072
    float* ye1    = ws + 524288;
    float* ye2    = ws + 524800;
    float* yx1    = ws + 525312;
    float* yx2    = ws + 525824;
    float* psum   = ws + 526336;
    float* psumsq = ws + 591872;
    float* pminb  = ws + 657408;
    float* pmaxb  = ws + 722944;
    float* za     = ws + 788480;
    float* zx     = ws + 789504;
    unsigned short* WaddT = (unsigned short*)(ws + 791552);  // 32768 u16
    unsigned short* WmulT = (unsigned short*)(ws + 807936);
    unsigned short* W2T   = (unsigned short*)(ws + 824320);

    float* xhat = (float*)d_out;
    float* ahat = (float*)d_out + 131072;
    float* yhat = (float*)d_out + 16908288;

    wt_kernel<<<384, 256, 0, stream>>>(a2x_add_w, a2x_mul_w, a_out_w, WaddT, WmulT, W2T);
    qkv_kernel<<<192, 256, 0, stream>>>(x, qw, qb, kw, kb, vw, vb, Q, kv);
    ymap_kernel<<<8, 256, 0, stream>>>(y, y2e_add_w, y2e_add_b, y2e_mul_w, y2e_mul_b,
                                       y2x_add_w, y2x_add_b, y2x_mul_w, y2x_mul_b,
                                       ye1, ye2, yx1, yx2);
    za_part_kernel<<<512, 128, 0, stream>>>(a, psum, psumsq, pminb, pmaxb);
    zx_kernel<<<2, 256, 0, stream>>>(x, zx);
    main_kernel<<<512, 512, 0, stream>>>(a, WaddT, a2x_add_b, WmulT, a2x_mul_b,
                                         W2T, a_out_b, Q, kv, ye1, ye2, ahat, wV);
    xhat_kernel<<<64, 256, 0, stream>>>(wV, yx1, yx2, x_out_w, x_out_b, xhat);
    za_reduce_kernel<<<2, 128, 0, stream>>>(psum, psumsq, pminb, pmaxb, za);
    yhat_kernel<<<2, 128, 0, stream>>>(y, za, zx, y_y_w, y_y_b, x_y_w, x_y_b, a_y_w, a_y_b,
                                       y_out1_w, y_out1_b, y_out2_w, y_out2_b, yhat);
}